// Round 9
// baseline (240.967 us; speedup 1.0000x reference)
//
#include <hip/hip_runtime.h>
#include <cstdint>
#include <cstddef>

typedef short v4s __attribute__((ext_vector_type(4)));
typedef short v8s __attribute__((ext_vector_type(8)));
typedef float v4f __attribute__((ext_vector_type(4)));

// fp32 -> bf16 round-to-nearest-even
__device__ __forceinline__ short f2bf(float f) {
    union { float f; unsigned u; } x; x.f = f;
    unsigned r = (x.u + 0x7FFFu + ((x.u >> 16) & 1u)) >> 16;
    return (short)(unsigned short)r;
}
__device__ __forceinline__ float bf2f(short h) {
    union { unsigned u; float f; } x; x.u = ((unsigned)(unsigned short)h) << 16;
    return x.f;
}

// async global->LDS, 16B per lane; LDS dest = wave-uniform base + lane*16
__device__ __forceinline__ void gld16(const void* g, void* l) {
    __builtin_amdgcn_global_load_lds((const __attribute__((address_space(1))) void*)g,
                                     (__attribute__((address_space(3))) void*)l, 16, 0, 0);
}

// ---------------------------------------------------------------- cvt fp32->bf16 (+ control zeroing)
__global__ __launch_bounds__(256) void cvt_bf16(
    const float* __restrict__ x, const float* __restrict__ wq, const float* __restrict__ wk,
    const float* __restrict__ wv, const float* __restrict__ wo,
    short* __restrict__ xb, short* __restrict__ wqb, short* __restrict__ wkb,
    short* __restrict__ wvb, short* __restrict__ wob, float* __restrict__ colsum,
    float* __restrict__ dtot, int* __restrict__ dcnt)
{
    int bid = blockIdx.x;
    const float* src; short* dst; size_t base;
    if (bid < 4096)      { src = x;  dst = xb;  base = (size_t)bid * 1024; }
    else if (bid < 5120) { src = wq; dst = wqb; base = (size_t)(bid - 4096) * 1024; }
    else if (bid < 6144) { src = wk; dst = wkb; base = (size_t)(bid - 5120) * 1024; }
    else if (bid < 7168) { src = wv; dst = wvb; base = (size_t)(bid - 6144) * 1024; }
    else                 { src = wo; dst = wob; base = (size_t)(bid - 7168) * 1024; }
    size_t idx = base + (size_t)threadIdx.x * 4;
    v4f v = *(const v4f*)(src + idx);
    v4s o;
    o[0] = f2bf(v[0]); o[1] = f2bf(v[1]); o[2] = f2bf(v[2]); o[3] = f2bf(v[3]);
    *(v4s*)(dst + idx) = o;
    if (bid == 0) {   // zero colsum + decov accumulators (replaces hipMemsetAsync dispatch)
        v4f z = {0.f, 0.f, 0.f, 0.f};
        *(v4f*)(colsum + (size_t)threadIdx.x * 4) = z;
        if (threadIdx.x == 0) { *dtot = 0.f; *dcnt = 0; }
    }
}

// ---------------------------------------------------------------- QKV projection GEMM (round-2 proven)
// y = x @ W^T + b, M=4096 N=1024 K=1024, bf16 MFMA 16x16x32, 128x128 tiles, BK=32.
// mode z: 0=q (1/8-scaled, [b,h,l,dk]), 1=k ([b,h,l,dk]), 2=v transposed ([b,h,dk,l]).
// NOTE (r7): direct 2B epilogue stores beat LDS-coalesced stores here — occupancy/L2-reuse first.
__global__ __launch_bounds__(256) void gemm_qkv(
    const short* __restrict__ xb,
    const short* __restrict__ wq, const short* __restrict__ wk, const short* __restrict__ wv,
    const float* __restrict__ bq, const float* __restrict__ bk, const float* __restrict__ bv,
    short* __restrict__ qo, short* __restrict__ ko, short* __restrict__ vto)
{
    __shared__ __align__(16) short At[128 * 32];
    __shared__ __align__(16) short Bt[128 * 32];
    const int K = 1024;
    const int mode = blockIdx.z;
    const short* W = (mode == 0) ? wq : (mode == 1) ? wk : wv;
    const float* bias = (mode == 0) ? bq : (mode == 1) ? bk : bv;
    const int m0 = blockIdx.y * 128, n0 = blockIdx.x * 128;
    const int tid = threadIdx.x, wave = tid >> 6, lane = tid & 63;
    const int quad = lane >> 4, ll = lane & 15;
    const int wr = wave >> 1, wc = wave & 1;
    const v4f zero4 = {0.f, 0.f, 0.f, 0.f};
    v4f acc[4][4];
    for (int i = 0; i < 4; ++i) for (int j = 0; j < 4; ++j) acc[i][j] = zero4;

    for (int k0 = 0; k0 < K; k0 += 32) {
        __syncthreads();
#pragma unroll
        for (int c = 0; c < 2; ++c) {
            int chb = (wave * 2 + c) * 64;
            int ch = chb + lane;
            int row = ch >> 2, col8 = (ch & 3) * 8;
            gld16(xb + (size_t)(m0 + row) * K + k0 + col8, &At[chb * 8]);
            gld16(W  + (size_t)(n0 + row) * K + k0 + col8, &Bt[chb * 8]);
        }
        __syncthreads();
        v8s af[4], bfr[4];
#pragma unroll
        for (int i = 0; i < 4; ++i) af[i]  = *(const v8s*)&At[(wr * 64 + i * 16 + ll) * 32 + quad * 8];
#pragma unroll
        for (int j = 0; j < 4; ++j) bfr[j] = *(const v8s*)&Bt[(wc * 64 + j * 16 + ll) * 32 + quad * 8];
#pragma unroll
        for (int i = 0; i < 4; ++i)
#pragma unroll
            for (int j = 0; j < 4; ++j)
                acc[i][j] = __builtin_amdgcn_mfma_f32_16x16x32_bf16(af[i], bfr[j], acc[i][j], 0, 0, 0);
    }

    const float scale = (mode == 0) ? 0.125f : 1.0f;
#pragma unroll
    for (int j = 0; j < 4; ++j) {
        int n = n0 + wc * 64 + j * 16 + ll;
        float bb = bias[n];
        int hh = n >> 6, dk = n & 63;
#pragma unroll
        for (int i = 0; i < 4; ++i) {
            int mbase = m0 + wr * 64 + i * 16 + quad * 4;
#pragma unroll
            for (int r = 0; r < 4; ++r) {
                int m = mbase + r;
                int b = m >> 10, li = m & 1023;
                short h = f2bf((acc[i][j][r] + bb) * scale);
                if (mode == 0)
                    qo[(((size_t)(b * 16 + hh) * 1024 + li) << 6) + dk] = h;
                else if (mode == 1)
                    ko[(((size_t)(b * 16 + hh) * 1024 + li) << 6) + dk] = h;
                else
                    vto[(((size_t)(b * 16 + hh) * 64 + dk) << 10) + li] = h;
            }
        }
    }
}

// ---------------------------------------------------------------- fused attention + column sums
// One block per (bh, 128-row q tile); 4 waves x 32 q-rows (2 m-subtiles). 64-key K/V tiles.
// Pt is WAVE-PRIVATE: no barrier between P-write and P-read -> 2 barriers/iter.
__global__ __launch_bounds__(256) void attn_flash(
    const short* __restrict__ qb, const short* __restrict__ kb, const short* __restrict__ vtb,
    float* __restrict__ merged, short* __restrict__ mergedh, float* __restrict__ colsum)
{
    __shared__ __align__(16) short Kt[64 * 64];     // [key j][dk], XOR-swizzled 16B granules
    __shared__ __align__(16) short Vt[64 * 64];     // [dk d][key j], XOR-swizzled
    __shared__ __align__(16) short Pt[4 * 32 * 68]; // per-wave 32x64 P tile, stride 68
    const int bh = blockIdx.y, qt = blockIdx.x;
    const int tid = threadIdx.x, wave = tid >> 6, lane = tid & 63;
    const int quad = lane >> 4, ll = lane & 15;
    const short* qp = qb  + (size_t)bh * 1024 * 64;
    const short* kp = kb  + (size_t)bh * 1024 * 64;
    const short* vp = vtb + (size_t)bh * 64 * 1024;

    v8s qa[2][2];
#pragma unroll
    for (int mi = 0; mi < 2; ++mi) {
        int qrow = qt * 128 + wave * 32 + mi * 16 + ll;
        qa[mi][0] = *(const v8s*)(qp + (size_t)qrow * 64 + quad * 8);
        qa[mi][1] = *(const v8s*)(qp + (size_t)qrow * 64 + 32 + quad * 8);
    }

    const v4f zero4 = {0.f, 0.f, 0.f, 0.f};
    v4f oacc[2][4];
    for (int mi = 0; mi < 2; ++mi) for (int nt = 0; nt < 4; ++nt) oacc[mi][nt] = zero4;
    float lsum[2][4];
    for (int mi = 0; mi < 2; ++mi) for (int r = 0; r < 4; ++r) lsum[mi][r] = 0.f;
    short* pw = &Pt[wave * 32 * 68];

    for (int jt = 0; jt < 16; ++jt) {
        __syncthreads();
#pragma unroll
        for (int c = 0; c < 2; ++c) {
            int chb = (wave * 2 + c) * 64;
            int ch = chb + lane;
            int row = ch >> 3;
            int gi = ((ch & 7) ^ (row & 7)) * 8;
            gld16(kp + (size_t)(jt * 64 + row) * 64 + gi, &Kt[chb * 8]);
            gld16(vp + (size_t)row * 1024 + jt * 64 + gi, &Vt[chb * 8]);
        }
        __syncthreads();

        v4f sacc[2][4];
#pragma unroll
        for (int nt = 0; nt < 4; ++nt) {
            int n = nt * 16 + ll;
            int g0 = (quad ^ (n & 7)) * 8;
            int g1 = ((4 + quad) ^ (n & 7)) * 8;
            v8s b0 = *(const v8s*)&Kt[n * 64 + g0];
            v8s b1 = *(const v8s*)&Kt[n * 64 + g1];
#pragma unroll
            for (int mi = 0; mi < 2; ++mi) {
                v4f s = zero4;
                s = __builtin_amdgcn_mfma_f32_16x16x32_bf16(qa[mi][0], b0, s, 0, 0, 0);
                s = __builtin_amdgcn_mfma_f32_16x16x32_bf16(qa[mi][1], b1, s, 0, 0, 0);
                sacc[mi][nt] = s;
            }
        }
#pragma unroll
        for (int mi = 0; mi < 2; ++mi)
#pragma unroll
            for (int nt = 0; nt < 4; ++nt)
#pragma unroll
                for (int r = 0; r < 4; ++r) {
                    float e = __expf(sacc[mi][nt][r]);
                    lsum[mi][r] += e;
                    pw[(mi * 16 + quad * 4 + r) * 68 + nt * 16 + ll] = f2bf(e);
                }
        // no __syncthreads: Pt is wave-private, DS ops are in-order within a wave
        v8s pa[2][2];
#pragma unroll
        for (int mi = 0; mi < 2; ++mi) {
            v4s p00 = *(const v4s*)&pw[(mi * 16 + ll) * 68 + quad * 8];
            v4s p01 = *(const v4s*)&pw[(mi * 16 + ll) * 68 + quad * 8 + 4];
            v4s p10 = *(const v4s*)&pw[(mi * 16 + ll) * 68 + 32 + quad * 8];
            v4s p11 = *(const v4s*)&pw[(mi * 16 + ll) * 68 + 32 + quad * 8 + 4];
            pa[mi][0] = __builtin_shufflevector(p00, p01, 0, 1, 2, 3, 4, 5, 6, 7);
            pa[mi][1] = __builtin_shufflevector(p10, p11, 0, 1, 2, 3, 4, 5, 6, 7);
        }
#pragma unroll
        for (int nt = 0; nt < 4; ++nt) {
            int n = nt * 16 + ll;
            int g0 = (quad ^ (n & 7)) * 8;
            int g1 = ((4 + quad) ^ (n & 7)) * 8;
            v8s v0 = *(const v8s*)&Vt[n * 64 + g0];
            v8s v1 = *(const v8s*)&Vt[n * 64 + g1];
#pragma unroll
            for (int mi = 0; mi < 2; ++mi) {
                oacc[mi][nt] = __builtin_amdgcn_mfma_f32_16x16x32_bf16(pa[mi][0], v0, oacc[mi][nt], 0, 0, 0);
                oacc[mi][nt] = __builtin_amdgcn_mfma_f32_16x16x32_bf16(pa[mi][1], v1, oacc[mi][nt], 0, 0, 0);
            }
        }
    }

    const int b = bh >> 4, h = bh & 15;
    float csum[4] = {0.f, 0.f, 0.f, 0.f};
#pragma unroll
    for (int mi = 0; mi < 2; ++mi) {
        float linv[4];
#pragma unroll
        for (int r = 0; r < 4; ++r) {
            float s = lsum[mi][r];
            s += __shfl_xor(s, 1); s += __shfl_xor(s, 2);
            s += __shfl_xor(s, 4); s += __shfl_xor(s, 8);
            linv[r] = 1.0f / s;
        }
#pragma unroll
        for (int r = 0; r < 4; ++r) {
            int li = qt * 128 + wave * 32 + mi * 16 + quad * 4 + r;
            size_t rowoff = ((size_t)(b * 1024 + li)) * 1024 + h * 64;
#pragma unroll
            for (int nt = 0; nt < 4; ++nt) {
                int d = nt * 16 + ll;
                float v = oacc[mi][nt][r] * linv[r];
                merged[rowoff + d] = v;
                mergedh[rowoff + d] = f2bf(v);
                csum[nt] += v;
            }
        }
    }
    // per-column partials: combine quads -> 32-row sums, one atomic per column/wave
#pragma unroll
    for (int nt = 0; nt < 4; ++nt) {
        csum[nt] += __shfl_xor(csum[nt], 16);
        csum[nt] += __shfl_xor(csum[nt], 32);
    }
    if (quad == 0) {
#pragma unroll
        for (int nt = 0; nt < 4; ++nt)
            atomicAdd(&colsum[h * 64 + nt * 16 + ll], csum[nt]);
    }
}

// ---------------------------------------------------------------- post-attn: out-proj GEMM + center/split/transpose
// blocks 0..255: out = mergedh @ Wo^T + bo (fp32). blocks 256..1279: center+transpose.
__global__ __launch_bounds__(256) void post_attn(
    const short* __restrict__ A, const short* __restrict__ W, const float* __restrict__ bias,
    float* __restrict__ out,
    const float* __restrict__ merged, const float* __restrict__ colsum,
    short* __restrict__ uth, short* __restrict__ utl)
{
    __shared__ __align__(16) char smem[18432];
    const int bid = blockIdx.x;
    const int tid = threadIdx.x;
    if (bid < 256) {
        short* At = (short*)smem;            // 8 KB
        short* Bt = (short*)(smem + 8192);   // 8 KB
        const int K = 1024;
        const int n0 = (bid & 7) * 128, m0 = (bid >> 3) * 128;
        const int wave = tid >> 6, lane = tid & 63;
        const int quad = lane >> 4, ll = lane & 15;
        const int wr = wave >> 1, wc = wave & 1;
        const v4f zero4 = {0.f, 0.f, 0.f, 0.f};
        v4f acc[4][4];
        for (int i = 0; i < 4; ++i) for (int j = 0; j < 4; ++j) acc[i][j] = zero4;

        for (int k0 = 0; k0 < K; k0 += 32) {
            __syncthreads();
#pragma unroll
            for (int c = 0; c < 2; ++c) {
                int chb = (wave * 2 + c) * 64;
                int ch = chb + lane;
                int row = ch >> 2, col8 = (ch & 3) * 8;
                gld16(A + (size_t)(m0 + row) * K + k0 + col8, &At[chb * 8]);
                gld16(W + (size_t)(n0 + row) * K + k0 + col8, &Bt[chb * 8]);
            }
            __syncthreads();
            v8s af[4], bfr[4];
#pragma unroll
            for (int i = 0; i < 4; ++i) af[i]  = *(const v8s*)&At[(wr * 64 + i * 16 + ll) * 32 + quad * 8];
#pragma unroll
            for (int j = 0; j < 4; ++j) bfr[j] = *(const v8s*)&Bt[(wc * 64 + j * 16 + ll) * 32 + quad * 8];
#pragma unroll
            for (int i = 0; i < 4; ++i)
#pragma unroll
                for (int j = 0; j < 4; ++j)
                    acc[i][j] = __builtin_amdgcn_mfma_f32_16x16x32_bf16(af[i], bfr[j], acc[i][j], 0, 0, 0);
        }

#pragma unroll
        for (int j = 0; j < 4; ++j) {
            int n = n0 + wc * 64 + j * 16 + ll;
            float bb = bias[n];
#pragma unroll
            for (int i = 0; i < 4; ++i) {
                int mbase = m0 + wr * 64 + i * 16 + quad * 4;
#pragma unroll
                for (int r = 0; r < 4; ++r) {
                    int m = mbase + r;
                    out[(size_t)m * 1024 + n] = acc[i][j][r] + bb;
                }
            }
        }
    } else {
        short (*Hh)[72] = (short(*)[72])smem;            // 9216 B
        short (*Hl)[72] = (short(*)[72])(smem + 9216);   // 9216 B
        const int cid = bid - 256;
        const int d0 = (cid & 15) * 64, m0 = (cid >> 4) * 64;
        const int r0 = tid >> 4, c4 = (tid & 15) * 4;
        float mu[4];
#pragma unroll
        for (int e = 0; e < 4; ++e) mu[e] = colsum[d0 + c4 + e] * (1.0f / 4096.0f);
        for (int rr = 0; rr < 64; rr += 16) {
            int m = m0 + rr + r0;
            v4f v = *(const v4f*)(merged + (size_t)m * 1024 + d0 + c4);
#pragma unroll
            for (int e = 0; e < 4; ++e) {
                float u = v[e] - mu[e];
                short h = f2bf(u);
                Hh[c4 + e][rr + r0] = h;
                Hl[c4 + e][rr + r0] = f2bf(u - bf2f(h));
            }
        }
        __syncthreads();
        const int d = tid >> 2, mg = (tid & 3) * 16;
        v8s a0, a1, b0, b1;
#pragma unroll
        for (int e = 0; e < 8; ++e) {
            a0[e] = Hh[d][mg + e]; a1[e] = Hh[d][mg + 8 + e];
            b0[e] = Hl[d][mg + e]; b1[e] = Hl[d][mg + 8 + e];
        }
        size_t off = (size_t)(d0 + d) * 4096 + m0 + mg;
        *(v8s*)(uth + off) = a0; *(v8s*)(uth + off + 8) = a1;
        *(v8s*)(utl + off) = b0; *(v8s*)(utl + off + 8) = b1;
    }
}

// ---------------------------------------------------------------- DeCov GEMM, 128x128 tiles, split-K
// C = Ut @ Ut^T, 8x8 grid of 128-tiles -> 36 upper-tri pairs, K=4096 -> 16 chunks of 256.
// Grid (36, 16) = 576 blocks. Per wave: 4x4 acc, 48 MFMA per BK=32 step (2x the old
// 64-tile density); each wave stages one of Ah/Al/Bh/Bl. Partials to cpart[chunk][pair].
__global__ __launch_bounds__(256) void gemm_decov(
    const short* __restrict__ uth, const short* __restrict__ utl, float* __restrict__ cpart)
{
    int p = blockIdx.x, I = 0, rem = p;
    while (rem >= 8 - I) { rem -= 8 - I; ++I; }
    const int J = I + rem;
    const int kbase = blockIdx.y * 256;
    __shared__ __align__(16) short Ah[128 * 32], Al[128 * 32], Bh[128 * 32], Bl[128 * 32];
    const int tid = threadIdx.x;
    const int wave = tid >> 6, lane = tid & 63;
    const int quad = lane >> 4, ll = lane & 15;
    const int wr = wave >> 1, wc = wave & 1;
    const v4f zero4 = {0.f, 0.f, 0.f, 0.f};
    v4f acc[4][4];
    for (int i = 0; i < 4; ++i) for (int j = 0; j < 4; ++j) acc[i][j] = zero4;

    // staging: wave 0->Ah(uth,I) 1->Al(utl,I) 2->Bh(uth,J) 3->Bl(utl,J)
    short* sarr = (wave == 0) ? Ah : (wave == 1) ? Al : (wave == 2) ? Bh : Bl;
    const short* gsrc = (wave & 1) ? utl : uth;
    const int rbase = ((wave < 2) ? I : J) * 128;
    const int srow = lane >> 2, scol = (lane & 3) * 8;

    for (int kk = 0; kk < 256; kk += 32) {
        int k0 = kbase + kk;
        __syncthreads();
#pragma unroll
        for (int c = 0; c < 8; ++c) {
            int row = c * 16 + srow;
            gld16(gsrc + (size_t)(rbase + row) * 4096 + k0 + scol, &sarr[c * 512]);
        }
        __syncthreads();
        v8s bh[4], bl[4];
#pragma unroll
        for (int j = 0; j < 4; ++j) {
            int ro = (wc * 64 + j * 16 + ll) * 32 + quad * 8;
            bh[j] = *(const v8s*)&Bh[ro];
            bl[j] = *(const v8s*)&Bl[ro];
        }
#pragma unroll
        for (int i = 0; i < 4; ++i) {
            int ro = (wr * 64 + i * 16 + ll) * 32 + quad * 8;
            v8s ah = *(const v8s*)&Ah[ro];
            v8s al = *(const v8s*)&Al[ro];
#pragma unroll
            for (int j = 0; j < 4; ++j) {
                acc[i][j] = __builtin_amdgcn_mfma_f32_16x16x32_bf16(ah, bh[j], acc[i][j], 0, 0, 0);
                acc[i][j] = __builtin_amdgcn_mfma_f32_16x16x32_bf16(ah, bl[j], acc[i][j], 0, 0, 0);
                acc[i][j] = __builtin_amdgcn_mfma_f32_16x16x32_bf16(al, bh[j], acc[i][j], 0, 0, 0);
            }
        }
    }

    float* dst = cpart + ((size_t)blockIdx.y * 36 + p) * 16384;
#pragma unroll
    for (int i = 0; i < 4; ++i)
#pragma unroll
        for (int j = 0; j < 4; ++j)
#pragma unroll
            for (int r = 0; r < 4; ++r) {
                int gi2 = wr * 64 + i * 16 + quad * 4 + r;
                int gj2 = wc * 64 + j * 16 + ll;
                dst[gi2 * 128 + gj2] = acc[i][j][r];
            }
}

// ---------------------------------------------------------------- DeCov reduce + final (atomic-only, no fences)
// Grid (36 pairs, 4 quarters) = 144 blocks. Off-diag tiles x2; diag tiles contain both
// orders so plain gi!=gj sum matches the ordered off-diagonal sum.
__global__ __launch_bounds__(256) void decov_reduce(
    const float* __restrict__ cpart, float* __restrict__ dtot, int* __restrict__ dcnt,
    float* __restrict__ out)
{
    int p = blockIdx.x, I = 0, rem = p;
    while (rem >= 8 - I) { rem -= 8 - I; ++I; }
    const int J = I + rem;
    const int t = threadIdx.x;
    const int ebase = blockIdx.y * 4096;
    __shared__ float wsums[4];
    float s = 0.f;
#pragma unroll
    for (int it = 0; it < 4; ++it) {
        int e4 = ebase + it * 1024 + t * 4;
        v4f c = {0.f, 0.f, 0.f, 0.f};
#pragma unroll
        for (int kc = 0; kc < 16; ++kc)
            c += *(const v4f*)&cpart[((size_t)kc * 36 + p) * 16384 + e4];
        int gi = I * 128 + (e4 >> 7), colb = J * 128 + (e4 & 127);
#pragma unroll
        for (int k = 0; k < 4; ++k) {
            float cv = c[k];
            if (gi != colb + k) s += cv * cv;
        }
    }
    if (I < J) s *= 2.f;
    s += __shfl_xor(s, 1); s += __shfl_xor(s, 2); s += __shfl_xor(s, 4);
    s += __shfl_xor(s, 8); s += __shfl_xor(s, 16); s += __shfl_xor(s, 32);
    if ((t & 63) == 0) wsums[t >> 6] = s;
    __syncthreads();
    if (t == 0) {
        float blk = wsums[0] + wsums[1] + wsums[2] + wsums[3];
        float o = atomicAdd(dtot, blk);
        // data-dependency on o forces the dtot RMW to complete (at L2, point of
        // coherence) before the counter RMW issues; no threadfence needed.
        int old = atomicAdd(dcnt, 1 + (int)(o * 0.0f));
        if (old == 143) {
            float tot = atomicAdd(dtot, 0.0f);   // RMW returns the coherent full sum
            // C = raw/4096; decov = 0.5 * sum_offdiag C^2
            out[4194304] = 0.5f * tot / (4096.0f * 4096.0f);
        }
    }
}

// ---------------------------------------------------------------- launch
extern "C" void kernel_launch(void* const* d_in, const int* in_sizes, int n_in,
                              void* d_out, int out_size, void* d_ws, size_t ws_size,
                              hipStream_t stream) {
    const float* x  = (const float*)d_in[0];
    const float* Wq = (const float*)d_in[1];
    const float* bq = (const float*)d_in[2];
    const float* Wk = (const float*)d_in[3];
    const float* bk = (const float*)d_in[4];
    const float* Wv = (const float*)d_in[5];
    const float* bv = (const float*)d_in[6];
    const float* Wo = (const float*)d_in[7];
    const float* bo = (const float*)d_in[8];
    float* out = (float*)d_out;
    char* ws = (char*)d_ws;
    const size_t MB = 1ull << 20;
    short* xb      = (short*)(ws);              //  8 MB [4096][1024]
    short* wqb     = (short*)(ws + 8  * MB);    //  2 MB
    short* wkb     = (short*)(ws + 10 * MB);
    short* wvb     = (short*)(ws + 12 * MB);
    short* wob     = (short*)(ws + 14 * MB);
    short* qb      = (short*)(ws + 16 * MB);    //  8 MB [bh][l][dk] (q pre-scaled 1/8)
    short* kb      = (short*)(ws + 24 * MB);    //  8 MB [bh][l][dk]
    short* vtb     = (short*)(ws + 32 * MB);    //  8 MB [bh][dk][l]
    float* merged  = (float*)(ws + 40 * MB);    // 16 MB [4096][1024] fp32
    short* mergedh = (short*)(ws + 56 * MB);    //  8 MB bf16
    short* uth     = (short*)(ws + 65 * MB);    //  8 MB [1024][4096]
    short* utl     = (short*)(ws + 73 * MB);    //  8 MB
    float* dtot    = (float*)(ws + 81 * MB);    //  4 B
    int*   dcnt    = (int*)(ws + 81 * MB + 64); //  4 B
    float* colsum  = (float*)(ws + 81 * MB + 4096); // 4 KB
    float* cpart   = (float*)(ws);              // 37.7 MB [16][36][16384] (reuses dead 0-40MB region)

    hipLaunchKernelGGL(cvt_bf16, dim3(8192), dim3(256), 0, stream,
                       x, Wq, Wk, Wv, Wo, xb, wqb, wkb, wvb, wob, colsum, dtot, dcnt);
    hipLaunchKernelGGL(gemm_qkv, dim3(8, 32, 3), dim3(256), 0, stream,
                       xb, wqb, wkb, wvb, bq, bk, bv, qb, kb, vtb);
    hipLaunchKernelGGL(attn_flash, dim3(8, 64), dim3(256), 0, stream,
                       qb, kb, vtb, merged, mergedh, colsum);
    hipLaunchKernelGGL(post_attn, dim3(1280), dim3(256), 0, stream,
                       mergedh, wob, bo, out, merged, colsum, uth, utl);
    hipLaunchKernelGGL(gemm_decov, dim3(36, 16), dim3(256), 0, stream, uth, utl, cpart);
    hipLaunchKernelGGL(decov_reduce, dim3(36, 4), dim3(256), 0, stream, cpart, dtot, dcnt, out);
}

// Round 10
// 239.199 us; speedup vs baseline: 1.0074x; 1.0074x over previous
//
#include <hip/hip_runtime.h>
#include <cstdint>
#include <cstddef>

typedef short v4s __attribute__((ext_vector_type(4)));
typedef short v8s __attribute__((ext_vector_type(8)));
typedef float v4f __attribute__((ext_vector_type(4)));

// fp32 -> bf16 round-to-nearest-even
__device__ __forceinline__ short f2bf(float f) {
    union { float f; unsigned u; } x; x.f = f;
    unsigned r = (x.u + 0x7FFFu + ((x.u >> 16) & 1u)) >> 16;
    return (short)(unsigned short)r;
}
__device__ __forceinline__ float bf2f(short h) {
    union { unsigned u; float f; } x; x.u = ((unsigned)(unsigned short)h) << 16;
    return x.f;
}

// async global->LDS, 16B per lane; LDS dest = wave-uniform base + lane*16
__device__ __forceinline__ void gld16(const void* g, void* l) {
    __builtin_amdgcn_global_load_lds((const __attribute__((address_space(1))) void*)g,
                                     (__attribute__((address_space(3))) void*)l, 16, 0, 0);
}

// ---------------------------------------------------------------- cvt fp32->bf16 (+ control zeroing)
__global__ __launch_bounds__(256) void cvt_bf16(
    const float* __restrict__ x, const float* __restrict__ wq, const float* __restrict__ wk,
    const float* __restrict__ wv, const float* __restrict__ wo,
    short* __restrict__ xb, short* __restrict__ wqb, short* __restrict__ wkb,
    short* __restrict__ wvb, short* __restrict__ wob, float* __restrict__ colsum,
    float* __restrict__ dtot, int* __restrict__ dcnt)
{
    int bid = blockIdx.x;
    const float* src; short* dst; size_t base;
    if (bid < 4096)      { src = x;  dst = xb;  base = (size_t)bid * 1024; }
    else if (bid < 5120) { src = wq; dst = wqb; base = (size_t)(bid - 4096) * 1024; }
    else if (bid < 6144) { src = wk; dst = wkb; base = (size_t)(bid - 5120) * 1024; }
    else if (bid < 7168) { src = wv; dst = wvb; base = (size_t)(bid - 6144) * 1024; }
    else                 { src = wo; dst = wob; base = (size_t)(bid - 7168) * 1024; }
    size_t idx = base + (size_t)threadIdx.x * 4;
    v4f v = *(const v4f*)(src + idx);
    v4s o;
    o[0] = f2bf(v[0]); o[1] = f2bf(v[1]); o[2] = f2bf(v[2]); o[3] = f2bf(v[3]);
    *(v4s*)(dst + idx) = o;
    if (bid == 0) {   // zero colsum + decov accumulators (replaces hipMemsetAsync dispatch)
        v4f z = {0.f, 0.f, 0.f, 0.f};
        *(v4f*)(colsum + (size_t)threadIdx.x * 4) = z;
        if (threadIdx.x == 0) { *dtot = 0.f; *dcnt = 0; }
    }
}

// ---------------------------------------------------------------- QKV projection GEMM (round-2 proven)
// y = x @ W^T + b, M=4096 N=1024 K=1024, bf16 MFMA 16x16x32, 128x128 tiles, BK=32.
// mode z: 0=q (scaled 1/8 * log2(e) so attn can use exp2, [b,h,l,dk]), 1=k, 2=v transposed.
// NOTE (r7): direct 2B epilogue stores beat LDS-coalesced stores here — occupancy/L2-reuse first.
__global__ __launch_bounds__(256) void gemm_qkv(
    const short* __restrict__ xb,
    const short* __restrict__ wq, const short* __restrict__ wk, const short* __restrict__ wv,
    const float* __restrict__ bq, const float* __restrict__ bk, const float* __restrict__ bv,
    short* __restrict__ qo, short* __restrict__ ko, short* __restrict__ vto)
{
    __shared__ __align__(16) short At[128 * 32];
    __shared__ __align__(16) short Bt[128 * 32];
    const int K = 1024;
    const int mode = blockIdx.z;
    const short* W = (mode == 0) ? wq : (mode == 1) ? wk : wv;
    const float* bias = (mode == 0) ? bq : (mode == 1) ? bk : bv;
    const int m0 = blockIdx.y * 128, n0 = blockIdx.x * 128;
    const int tid = threadIdx.x, wave = tid >> 6, lane = tid & 63;
    const int quad = lane >> 4, ll = lane & 15;
    const int wr = wave >> 1, wc = wave & 1;
    const v4f zero4 = {0.f, 0.f, 0.f, 0.f};
    v4f acc[4][4];
    for (int i = 0; i < 4; ++i) for (int j = 0; j < 4; ++j) acc[i][j] = zero4;

    for (int k0 = 0; k0 < K; k0 += 32) {
        __syncthreads();
#pragma unroll
        for (int c = 0; c < 2; ++c) {
            int chb = (wave * 2 + c) * 64;
            int ch = chb + lane;
            int row = ch >> 2, col8 = (ch & 3) * 8;
            gld16(xb + (size_t)(m0 + row) * K + k0 + col8, &At[chb * 8]);
            gld16(W  + (size_t)(n0 + row) * K + k0 + col8, &Bt[chb * 8]);
        }
        __syncthreads();
        v8s af[4], bfr[4];
#pragma unroll
        for (int i = 0; i < 4; ++i) af[i]  = *(const v8s*)&At[(wr * 64 + i * 16 + ll) * 32 + quad * 8];
#pragma unroll
        for (int j = 0; j < 4; ++j) bfr[j] = *(const v8s*)&Bt[(wc * 64 + j * 16 + ll) * 32 + quad * 8];
#pragma unroll
        for (int i = 0; i < 4; ++i)
#pragma unroll
            for (int j = 0; j < 4; ++j)
                acc[i][j] = __builtin_amdgcn_mfma_f32_16x16x32_bf16(af[i], bfr[j], acc[i][j], 0, 0, 0);
    }

    // mode 0: fold 1/sqrt(dk) AND log2(e) into q so attention uses exp2 directly
    const float scale = (mode == 0) ? 0.125f * 1.44269504f : 1.0f;
#pragma unroll
    for (int j = 0; j < 4; ++j) {
        int n = n0 + wc * 64 + j * 16 + ll;
        float bb = bias[n];
        int hh = n >> 6, dk = n & 63;
#pragma unroll
        for (int i = 0; i < 4; ++i) {
            int mbase = m0 + wr * 64 + i * 16 + quad * 4;
#pragma unroll
            for (int r = 0; r < 4; ++r) {
                int m = mbase + r;
                int b = m >> 10, li = m & 1023;
                short h = f2bf((acc[i][j][r] + bb) * scale);
                if (mode == 0)
                    qo[(((size_t)(b * 16 + hh) * 1024 + li) << 6) + dk] = h;
                else if (mode == 1)
                    ko[(((size_t)(b * 16 + hh) * 1024 + li) << 6) + dk] = h;
                else
                    vto[(((size_t)(b * 16 + hh) * 64 + dk) << 10) + li] = h;
            }
        }
    }
}

// ---------------------------------------------------------------- fused attention + column sums
// Grid (bh=64 fastest, qt=8): XCD = bh%8 heuristic puts all 8 q-tile blocks sharing one
// bh's K/V on the same XCD (2 MB working set < 4 MB L2). 128 keys staged per barrier
// pair (two 64-key sub-tiles), existing 64-key body runs twice -> barriers halve.
// Pt is WAVE-PRIVATE: no barrier between P-write and P-read.
__global__ __launch_bounds__(256) void attn_flash(
    const short* __restrict__ qb, const short* __restrict__ kb, const short* __restrict__ vtb,
    float* __restrict__ merged, short* __restrict__ mergedh, float* __restrict__ colsum)
{
    __shared__ __align__(16) short Kt[2 * 64 * 64];  // two [key j][dk] sub-tiles, XOR-swizzled
    __shared__ __align__(16) short Vt[2 * 64 * 64];  // two [dk d][key j] sub-tiles, XOR-swizzled
    __shared__ __align__(16) short Pt[4 * 32 * 68];  // per-wave 32x64 P tile, stride 68
    const int bh = blockIdx.x, qt = blockIdx.y;
    const int tid = threadIdx.x, wave = tid >> 6, lane = tid & 63;
    const int quad = lane >> 4, ll = lane & 15;
    const short* qp = qb  + (size_t)bh * 1024 * 64;
    const short* kp = kb  + (size_t)bh * 1024 * 64;
    const short* vp = vtb + (size_t)bh * 64 * 1024;

    v8s qa[2][2];
#pragma unroll
    for (int mi = 0; mi < 2; ++mi) {
        int qrow = qt * 128 + wave * 32 + mi * 16 + ll;
        qa[mi][0] = *(const v8s*)(qp + (size_t)qrow * 64 + quad * 8);
        qa[mi][1] = *(const v8s*)(qp + (size_t)qrow * 64 + 32 + quad * 8);
    }

    const v4f zero4 = {0.f, 0.f, 0.f, 0.f};
    v4f oacc[2][4];
    for (int mi = 0; mi < 2; ++mi) for (int nt = 0; nt < 4; ++nt) oacc[mi][nt] = zero4;
    float lsum[2][4];
    for (int mi = 0; mi < 2; ++mi) for (int r = 0; r < 4; ++r) lsum[mi][r] = 0.f;
    short* pw = &Pt[wave * 32 * 68];

    for (int jt2 = 0; jt2 < 8; ++jt2) {
        __syncthreads();
#pragma unroll
        for (int half = 0; half < 2; ++half) {
            int jt = jt2 * 2 + half;
#pragma unroll
            for (int c = 0; c < 2; ++c) {
                int chb = (wave * 2 + c) * 64;
                int ch = chb + lane;
                int row = ch >> 3;
                int gi = ((ch & 7) ^ (row & 7)) * 8;
                gld16(kp + (size_t)(jt * 64 + row) * 64 + gi, &Kt[half * 4096 + chb * 8]);
                gld16(vp + (size_t)row * 1024 + jt * 64 + gi, &Vt[half * 4096 + chb * 8]);
            }
        }
        __syncthreads();

#pragma unroll
        for (int half = 0; half < 2; ++half) {
            const short* Kh = &Kt[half * 4096];
            const short* Vh = &Vt[half * 4096];
            v4f sacc[2][4];
#pragma unroll
            for (int nt = 0; nt < 4; ++nt) {
                int n = nt * 16 + ll;
                int g0 = (quad ^ (n & 7)) * 8;
                int g1 = ((4 + quad) ^ (n & 7)) * 8;
                v8s b0 = *(const v8s*)&Kh[n * 64 + g0];
                v8s b1 = *(const v8s*)&Kh[n * 64 + g1];
#pragma unroll
                for (int mi = 0; mi < 2; ++mi) {
                    v4f s = zero4;
                    s = __builtin_amdgcn_mfma_f32_16x16x32_bf16(qa[mi][0], b0, s, 0, 0, 0);
                    s = __builtin_amdgcn_mfma_f32_16x16x32_bf16(qa[mi][1], b1, s, 0, 0, 0);
                    sacc[mi][nt] = s;
                }
            }
#pragma unroll
            for (int mi = 0; mi < 2; ++mi)
#pragma unroll
                for (int nt = 0; nt < 4; ++nt)
#pragma unroll
                    for (int r = 0; r < 4; ++r) {
                        float e = exp2f(sacc[mi][nt][r]);  // q pre-scaled by log2(e)
                        lsum[mi][r] += e;
                        pw[(mi * 16 + quad * 4 + r) * 68 + nt * 16 + ll] = f2bf(e);
                    }
            // no __syncthreads: Pt is wave-private, DS ops are in-order within a wave
            v8s pa[2][2];
#pragma unroll
            for (int mi = 0; mi < 2; ++mi) {
                v4s p00 = *(const v4s*)&pw[(mi * 16 + ll) * 68 + quad * 8];
                v4s p01 = *(const v4s*)&pw[(mi * 16 + ll) * 68 + quad * 8 + 4];
                v4s p10 = *(const v4s*)&pw[(mi * 16 + ll) * 68 + 32 + quad * 8];
                v4s p11 = *(const v4s*)&pw[(mi * 16 + ll) * 68 + 32 + quad * 8 + 4];
                pa[mi][0] = __builtin_shufflevector(p00, p01, 0, 1, 2, 3, 4, 5, 6, 7);
                pa[mi][1] = __builtin_shufflevector(p10, p11, 0, 1, 2, 3, 4, 5, 6, 7);
            }
#pragma unroll
            for (int nt = 0; nt < 4; ++nt) {
                int n = nt * 16 + ll;
                int g0 = (quad ^ (n & 7)) * 8;
                int g1 = ((4 + quad) ^ (n & 7)) * 8;
                v8s v0 = *(const v8s*)&Vh[n * 64 + g0];
                v8s v1 = *(const v8s*)&Vh[n * 64 + g1];
#pragma unroll
                for (int mi = 0; mi < 2; ++mi) {
                    oacc[mi][nt] = __builtin_amdgcn_mfma_f32_16x16x32_bf16(pa[mi][0], v0, oacc[mi][nt], 0, 0, 0);
                    oacc[mi][nt] = __builtin_amdgcn_mfma_f32_16x16x32_bf16(pa[mi][1], v1, oacc[mi][nt], 0, 0, 0);
                }
            }
        }
    }

    const int b = bh >> 4, h = bh & 15;
    float csum[4] = {0.f, 0.f, 0.f, 0.f};
#pragma unroll
    for (int mi = 0; mi < 2; ++mi) {
        float linv[4];
#pragma unroll
        for (int r = 0; r < 4; ++r) {
            float s = lsum[mi][r];
            s += __shfl_xor(s, 1); s += __shfl_xor(s, 2);
            s += __shfl_xor(s, 4); s += __shfl_xor(s, 8);
            linv[r] = 1.0f / s;
        }
#pragma unroll
        for (int r = 0; r < 4; ++r) {
            int li = qt * 128 + wave * 32 + mi * 16 + quad * 4 + r;
            size_t rowoff = ((size_t)(b * 1024 + li)) * 1024 + h * 64;
#pragma unroll
            for (int nt = 0; nt < 4; ++nt) {
                int d = nt * 16 + ll;
                float v = oacc[mi][nt][r] * linv[r];
                merged[rowoff + d] = v;
                mergedh[rowoff + d] = f2bf(v);
                csum[nt] += v;
            }
        }
    }
    // per-column partials: combine quads -> 32-row sums, one atomic per column/wave
#pragma unroll
    for (int nt = 0; nt < 4; ++nt) {
        csum[nt] += __shfl_xor(csum[nt], 16);
        csum[nt] += __shfl_xor(csum[nt], 32);
    }
    if (quad == 0) {
#pragma unroll
        for (int nt = 0; nt < 4; ++nt)
            atomicAdd(&colsum[h * 64 + nt * 16 + ll], csum[nt]);
    }
}

// ---------------------------------------------------------------- post-attn: out-proj GEMM + center/split/transpose
// blocks 0..255: out = mergedh @ Wo^T + bo (fp32). blocks 256..1279: center+transpose.
__global__ __launch_bounds__(256) void post_attn(
    const short* __restrict__ A, const short* __restrict__ W, const float* __restrict__ bias,
    float* __restrict__ out,
    const float* __restrict__ merged, const float* __restrict__ colsum,
    short* __restrict__ uth, short* __restrict__ utl)
{
    __shared__ __align__(16) char smem[18432];
    const int bid = blockIdx.x;
    const int tid = threadIdx.x;
    if (bid < 256) {
        short* At = (short*)smem;            // 8 KB
        short* Bt = (short*)(smem + 8192);   // 8 KB
        const int K = 1024;
        const int n0 = (bid & 7) * 128, m0 = (bid >> 3) * 128;
        const int wave = tid >> 6, lane = tid & 63;
        const int quad = lane >> 4, ll = lane & 15;
        const int wr = wave >> 1, wc = wave & 1;
        const v4f zero4 = {0.f, 0.f, 0.f, 0.f};
        v4f acc[4][4];
        for (int i = 0; i < 4; ++i) for (int j = 0; j < 4; ++j) acc[i][j] = zero4;

        for (int k0 = 0; k0 < K; k0 += 32) {
            __syncthreads();
#pragma unroll
            for (int c = 0; c < 2; ++c) {
                int chb = (wave * 2 + c) * 64;
                int ch = chb + lane;
                int row = ch >> 2, col8 = (ch & 3) * 8;
                gld16(A + (size_t)(m0 + row) * K + k0 + col8, &At[chb * 8]);
                gld16(W + (size_t)(n0 + row) * K + k0 + col8, &Bt[chb * 8]);
            }
            __syncthreads();
            v8s af[4], bfr[4];
#pragma unroll
            for (int i = 0; i < 4; ++i) af[i]  = *(const v8s*)&At[(wr * 64 + i * 16 + ll) * 32 + quad * 8];
#pragma unroll
            for (int j = 0; j < 4; ++j) bfr[j] = *(const v8s*)&Bt[(wc * 64 + j * 16 + ll) * 32 + quad * 8];
#pragma unroll
            for (int i = 0; i < 4; ++i)
#pragma unroll
                for (int j = 0; j < 4; ++j)
                    acc[i][j] = __builtin_amdgcn_mfma_f32_16x16x32_bf16(af[i], bfr[j], acc[i][j], 0, 0, 0);
        }

#pragma unroll
        for (int j = 0; j < 4; ++j) {
            int n = n0 + wc * 64 + j * 16 + ll;
            float bb = bias[n];
#pragma unroll
            for (int i = 0; i < 4; ++i) {
                int mbase = m0 + wr * 64 + i * 16 + quad * 4;
#pragma unroll
                for (int r = 0; r < 4; ++r) {
                    int m = mbase + r;
                    out[(size_t)m * 1024 + n] = acc[i][j][r] + bb;
                }
            }
        }
    } else {
        short (*Hh)[72] = (short(*)[72])smem;            // 9216 B
        short (*Hl)[72] = (short(*)[72])(smem + 9216);   // 9216 B
        const int cid = bid - 256;
        const int d0 = (cid & 15) * 64, m0 = (cid >> 4) * 64;
        const int r0 = tid >> 4, c4 = (tid & 15) * 4;
        float mu[4];
#pragma unroll
        for (int e = 0; e < 4; ++e) mu[e] = colsum[d0 + c4 + e] * (1.0f / 4096.0f);
        for (int rr = 0; rr < 64; rr += 16) {
            int m = m0 + rr + r0;
            v4f v = *(const v4f*)(merged + (size_t)m * 1024 + d0 + c4);
#pragma unroll
            for (int e = 0; e < 4; ++e) {
                float u = v[e] - mu[e];
                short h = f2bf(u);
                Hh[c4 + e][rr + r0] = h;
                Hl[c4 + e][rr + r0] = f2bf(u - bf2f(h));
            }
        }
        __syncthreads();
        const int d = tid >> 2, mg = (tid & 3) * 16;
        v8s a0, a1, b0, b1;
#pragma unroll
        for (int e = 0; e < 8; ++e) {
            a0[e] = Hh[d][mg + e]; a1[e] = Hh[d][mg + 8 + e];
            b0[e] = Hl[d][mg + e]; b1[e] = Hl[d][mg + 8 + e];
        }
        size_t off = (size_t)(d0 + d) * 4096 + m0 + mg;
        *(v8s*)(uth + off) = a0; *(v8s*)(uth + off + 8) = a1;
        *(v8s*)(utl + off) = b0; *(v8s*)(utl + off + 8) = b1;
    }
}

// ---------------------------------------------------------------- DeCov GEMM, 128x128 tiles, split-K
// C = Ut @ Ut^T, 8x8 grid of 128-tiles -> 36 upper-tri pairs, K=4096 -> 16 chunks of 256.
__global__ __launch_bounds__(256) void gemm_decov(
    const short* __restrict__ uth, const short* __restrict__ utl, float* __restrict__ cpart)
{
    int p = blockIdx.x, I = 0, rem = p;
    while (rem >= 8 - I) { rem -= 8 - I; ++I; }
    const int J = I + rem;
    const int kbase = blockIdx.y * 256;
    __shared__ __align__(16) short Ah[128 * 32], Al[128 * 32], Bh[128 * 32], Bl[128 * 32];
    const int tid = threadIdx.x;
    const int wave = tid >> 6, lane = tid & 63;
    const int quad = lane >> 4, ll = lane & 15;
    const int wr = wave >> 1, wc = wave & 1;
    const v4f zero4 = {0.f, 0.f, 0.f, 0.f};
    v4f acc[4][4];
    for (int i = 0; i < 4; ++i) for (int j = 0; j < 4; ++j) acc[i][j] = zero4;

    // staging: wave 0->Ah(uth,I) 1->Al(utl,I) 2->Bh(uth,J) 3->Bl(utl,J)
    short* sarr = (wave == 0) ? Ah : (wave == 1) ? Al : (wave == 2) ? Bh : Bl;
    const short* gsrc = (wave & 1) ? utl : uth;
    const int rbase = ((wave < 2) ? I : J) * 128;
    const int srow = lane >> 2, scol = (lane & 3) * 8;

    for (int kk = 0; kk < 256; kk += 32) {
        int k0 = kbase + kk;
        __syncthreads();
#pragma unroll
        for (int c = 0; c < 8; ++c) {
            int row = c * 16 + srow;
            gld16(gsrc + (size_t)(rbase + row) * 4096 + k0 + scol, &sarr[c * 512]);
        }
        __syncthreads();
        v8s bh[4], bl[4];
#pragma unroll
        for (int j = 0; j < 4; ++j) {
            int ro = (wc * 64 + j * 16 + ll) * 32 + quad * 8;
            bh[j] = *(const v8s*)&Bh[ro];
            bl[j] = *(const v8s*)&Bl[ro];
        }
#pragma unroll
        for (int i = 0; i < 4; ++i) {
            int ro = (wr * 64 + i * 16 + ll) * 32 + quad * 8;
            v8s ah = *(const v8s*)&Ah[ro];
            v8s al = *(const v8s*)&Al[ro];
#pragma unroll
            for (int j = 0; j < 4; ++j) {
                acc[i][j] = __builtin_amdgcn_mfma_f32_16x16x32_bf16(ah, bh[j], acc[i][j], 0, 0, 0);
                acc[i][j] = __builtin_amdgcn_mfma_f32_16x16x32_bf16(ah, bl[j], acc[i][j], 0, 0, 0);
                acc[i][j] = __builtin_amdgcn_mfma_f32_16x16x32_bf16(al, bh[j], acc[i][j], 0, 0, 0);
            }
        }
    }

    float* dst = cpart + ((size_t)blockIdx.y * 36 + p) * 16384;
#pragma unroll
    for (int i = 0; i < 4; ++i)
#pragma unroll
        for (int j = 0; j < 4; ++j)
#pragma unroll
            for (int r = 0; r < 4; ++r) {
                int gi2 = wr * 64 + i * 16 + quad * 4 + r;
                int gj2 = wc * 64 + j * 16 + ll;
                dst[gi2 * 128 + gj2] = acc[i][j][r];
            }
}

// ---------------------------------------------------------------- DeCov reduce + final (atomic-only, no fences)
__global__ __launch_bounds__(256) void decov_reduce(
    const float* __restrict__ cpart, float* __restrict__ dtot, int* __restrict__ dcnt,
    float* __restrict__ out)
{
    int p = blockIdx.x, I = 0, rem = p;
    while (rem >= 8 - I) { rem -= 8 - I; ++I; }
    const int J = I + rem;
    const int t = threadIdx.x;
    const int ebase = blockIdx.y * 4096;
    __shared__ float wsums[4];
    float s = 0.f;
#pragma unroll
    for (int it = 0; it < 4; ++it) {
        int e4 = ebase + it * 1024 + t * 4;
        v4f c = {0.f, 0.f, 0.f, 0.f};
#pragma unroll
        for (int kc = 0; kc < 16; ++kc)
            c += *(const v4f*)&cpart[((size_t)kc * 36 + p) * 16384 + e4];
        int gi = I * 128 + (e4 >> 7), colb = J * 128 + (e4 & 127);
#pragma unroll
        for (int k = 0; k < 4; ++k) {
            float cv = c[k];
            if (gi != colb + k) s += cv * cv;
        }
    }
    if (I < J) s *= 2.f;
    s += __shfl_xor(s, 1); s += __shfl_xor(s, 2); s += __shfl_xor(s, 4);
    s += __shfl_xor(s, 8); s += __shfl_xor(s, 16); s += __shfl_xor(s, 32);
    if ((t & 63) == 0) wsums[t >> 6] = s;
    __syncthreads();
    if (t == 0) {
        float blk = wsums[0] + wsums[1] + wsums[2] + wsums[3];
        float o = atomicAdd(dtot, blk);
        int old = atomicAdd(dcnt, 1 + (int)(o * 0.0f));
        if (old == 143) {
            float tot = atomicAdd(dtot, 0.0f);   // RMW returns the coherent full sum
            // C = raw/4096; decov = 0.5 * sum_offdiag C^2
            out[4194304] = 0.5f * tot / (4096.0f * 4096.0f);
        }
    }
}

// ---------------------------------------------------------------- launch
extern "C" void kernel_launch(void* const* d_in, const int* in_sizes, int n_in,
                              void* d_out, int out_size, void* d_ws, size_t ws_size,
                              hipStream_t stream) {
    const float* x  = (const float*)d_in[0];
    const float* Wq = (const float*)d_in[1];
    const float* bq = (const float*)d_in[2];
    const float* Wk = (const float*)d_in[3];
    const float* bk = (const float*)d_in[4];
    const float* Wv = (const float*)d_in[5];
    const float* bv = (const float*)d_in[6];
    const float* Wo = (const float*)d_in[7];
    const float* bo = (const float*)d_in[8];
    float* out = (float*)d_out;
    char* ws = (char*)d_ws;
    const size_t MB = 1ull << 20;
    short* xb      = (short*)(ws);              //  8 MB [4096][1024]
    short* wqb     = (short*)(ws + 8  * MB);    //  2 MB
    short* wkb     = (short*)(ws + 10 * MB);
    short* wvb     = (short*)(ws + 12 * MB);
    short* wob     = (short*)(ws + 14 * MB);
    short* qb      = (short*)(ws + 16 * MB);    //  8 MB [bh][l][dk] (q pre-scaled 1/8*log2e)
    short* kb      = (short*)(ws + 24 * MB);    //  8 MB [bh][l][dk]
    short* vtb     = (short*)(ws + 32 * MB);    //  8 MB [bh][dk][l]
    float* merged  = (float*)(ws + 40 * MB);    // 16 MB [4096][1024] fp32
    short* mergedh = (short*)(ws + 56 * MB);    //  8 MB bf16
    short* uth     = (short*)(ws + 65 * MB);    //  8 MB [1024][4096]
    short* utl     = (short*)(ws + 73 * MB);    //  8 MB
    float* dtot    = (float*)(ws + 81 * MB);    //  4 B
    int*   dcnt    = (int*)(ws + 81 * MB + 64); //  4 B
    float* colsum  = (float*)(ws + 81 * MB + 4096); // 4 KB
    float* cpart   = (float*)(ws);              // 37.7 MB [16][36][16384] (reuses dead 0-40MB region)

    hipLaunchKernelGGL(cvt_bf16, dim3(8192), dim3(256), 0, stream,
                       x, Wq, Wk, Wv, Wo, xb, wqb, wkb, wvb, wob, colsum, dtot, dcnt);
    hipLaunchKernelGGL(gemm_qkv, dim3(8, 32, 3), dim3(256), 0, stream,
                       xb, wqb, wkb, wvb, bq, bk, bv, qb, kb, vtb);
    hipLaunchKernelGGL(attn_flash, dim3(64, 8), dim3(256), 0, stream,
                       qb, kb, vtb, merged, mergedh, colsum);
    hipLaunchKernelGGL(post_attn, dim3(1280), dim3(256), 0, stream,
                       mergedh, wob, bo, out, merged, colsum, uth, utl);
    hipLaunchKernelGGL(gemm_decov, dim3(36, 16), dim3(256), 0, stream, uth, utl, cpart);
    hipLaunchKernelGGL(decov_reduce, dim3(36, 4), dim3(256), 0, stream, cpart, dtot, dcnt, out);
}

// Round 11
// 234.044 us; speedup vs baseline: 1.0296x; 1.0220x over previous
//
#include <hip/hip_runtime.h>
#include <cstdint>
#include <cstddef>

typedef short v4s __attribute__((ext_vector_type(4)));
typedef short v8s __attribute__((ext_vector_type(8)));
typedef float v4f __attribute__((ext_vector_type(4)));

// fp32 -> bf16 round-to-nearest-even
__device__ __forceinline__ short f2bf(float f) {
    union { float f; unsigned u; } x; x.f = f;
    unsigned r = (x.u + 0x7FFFu + ((x.u >> 16) & 1u)) >> 16;
    return (short)(unsigned short)r;
}
__device__ __forceinline__ float bf2f(short h) {
    union { unsigned u; float f; } x; x.u = ((unsigned)(unsigned short)h) << 16;
    return x.f;
}

// async global->LDS, 16B per lane; LDS dest = wave-uniform base + lane*16
__device__ __forceinline__ void gld16(const void* g, void* l) {
    __builtin_amdgcn_global_load_lds((const __attribute__((address_space(1))) void*)g,
                                     (__attribute__((address_space(3))) void*)l, 16, 0, 0);
}

// ---------------------------------------------------------------- cvt fp32->bf16 (+ control zeroing)
__global__ __launch_bounds__(256) void cvt_bf16(
    const float* __restrict__ x, const float* __restrict__ wq, const float* __restrict__ wk,
    const float* __restrict__ wv, const float* __restrict__ wo,
    short* __restrict__ xb, short* __restrict__ wqb, short* __restrict__ wkb,
    short* __restrict__ wvb, short* __restrict__ wob, float* __restrict__ colsum,
    float* __restrict__ dtot, int* __restrict__ dcnt)
{
    int bid = blockIdx.x;
    const float* src; short* dst; size_t base;
    if (bid < 4096)      { src = x;  dst = xb;  base = (size_t)bid * 1024; }
    else if (bid < 5120) { src = wq; dst = wqb; base = (size_t)(bid - 4096) * 1024; }
    else if (bid < 6144) { src = wk; dst = wkb; base = (size_t)(bid - 5120) * 1024; }
    else if (bid < 7168) { src = wv; dst = wvb; base = (size_t)(bid - 6144) * 1024; }
    else                 { src = wo; dst = wob; base = (size_t)(bid - 7168) * 1024; }
    size_t idx = base + (size_t)threadIdx.x * 4;
    v4f v = *(const v4f*)(src + idx);
    v4s o;
    o[0] = f2bf(v[0]); o[1] = f2bf(v[1]); o[2] = f2bf(v[2]); o[3] = f2bf(v[3]);
    *(v4s*)(dst + idx) = o;
    if (bid == 0) {   // zero colsum + decov accumulators (replaces hipMemsetAsync dispatch)
        v4f z = {0.f, 0.f, 0.f, 0.f};
        *(v4f*)(colsum + (size_t)threadIdx.x * 4) = z;
        if (threadIdx.x == 0) { *dtot = 0.f; *dcnt = 0; }
    }
}

// ---------------------------------------------------------------- QKV projection GEMM (round-2 proven)
// y = x @ W^T + b, M=4096 N=1024 K=1024, bf16 MFMA 16x16x32, 128x128 tiles, BK=32.
// mode z: 0=q (scaled 1/8 * log2(e) so attn can use raw v_exp, [b,h,l,dk]), 1=k, 2=v transposed.
// NOTE (r7): direct 2B epilogue stores beat LDS-coalesced stores here — occupancy/L2-reuse first.
__global__ __launch_bounds__(256) void gemm_qkv(
    const short* __restrict__ xb,
    const short* __restrict__ wq, const short* __restrict__ wk, const short* __restrict__ wv,
    const float* __restrict__ bq, const float* __restrict__ bk, const float* __restrict__ bv,
    short* __restrict__ qo, short* __restrict__ ko, short* __restrict__ vto)
{
    __shared__ __align__(16) short At[128 * 32];
    __shared__ __align__(16) short Bt[128 * 32];
    const int K = 1024;
    const int mode = blockIdx.z;
    const short* W = (mode == 0) ? wq : (mode == 1) ? wk : wv;
    const float* bias = (mode == 0) ? bq : (mode == 1) ? bk : bv;
    const int m0 = blockIdx.y * 128, n0 = blockIdx.x * 128;
    const int tid = threadIdx.x, wave = tid >> 6, lane = tid & 63;
    const int quad = lane >> 4, ll = lane & 15;
    const int wr = wave >> 1, wc = wave & 1;
    const v4f zero4 = {0.f, 0.f, 0.f, 0.f};
    v4f acc[4][4];
    for (int i = 0; i < 4; ++i) for (int j = 0; j < 4; ++j) acc[i][j] = zero4;

    for (int k0 = 0; k0 < K; k0 += 32) {
        __syncthreads();
#pragma unroll
        for (int c = 0; c < 2; ++c) {
            int chb = (wave * 2 + c) * 64;
            int ch = chb + lane;
            int row = ch >> 2, col8 = (ch & 3) * 8;
            gld16(xb + (size_t)(m0 + row) * K + k0 + col8, &At[chb * 8]);
            gld16(W  + (size_t)(n0 + row) * K + k0 + col8, &Bt[chb * 8]);
        }
        __syncthreads();
        v8s af[4], bfr[4];
#pragma unroll
        for (int i = 0; i < 4; ++i) af[i]  = *(const v8s*)&At[(wr * 64 + i * 16 + ll) * 32 + quad * 8];
#pragma unroll
        for (int j = 0; j < 4; ++j) bfr[j] = *(const v8s*)&Bt[(wc * 64 + j * 16 + ll) * 32 + quad * 8];
#pragma unroll
        for (int i = 0; i < 4; ++i)
#pragma unroll
            for (int j = 0; j < 4; ++j)
                acc[i][j] = __builtin_amdgcn_mfma_f32_16x16x32_bf16(af[i], bfr[j], acc[i][j], 0, 0, 0);
    }

    // mode 0: fold 1/sqrt(dk) AND log2(e) into q so attention uses raw v_exp directly
    const float scale = (mode == 0) ? 0.125f * 1.44269504f : 1.0f;
#pragma unroll
    for (int j = 0; j < 4; ++j) {
        int n = n0 + wc * 64 + j * 16 + ll;
        float bb = bias[n];
        int hh = n >> 6, dk = n & 63;
#pragma unroll
        for (int i = 0; i < 4; ++i) {
            int mbase = m0 + wr * 64 + i * 16 + quad * 4;
#pragma unroll
            for (int r = 0; r < 4; ++r) {
                int m = mbase + r;
                int b = m >> 10, li = m & 1023;
                short h = f2bf((acc[i][j][r] + bb) * scale);
                if (mode == 0)
                    qo[(((size_t)(b * 16 + hh) * 1024 + li) << 6) + dk] = h;
                else if (mode == 1)
                    ko[(((size_t)(b * 16 + hh) * 1024 + li) << 6) + dk] = h;
                else
                    vto[(((size_t)(b * 16 + hh) * 64 + dk) << 10) + li] = h;
            }
        }
    }
}

// ---------------------------------------------------------------- fused attention + column sums
// Grid (bh=64 fastest, qt=8): XCD = bh%8 puts all 8 q-tile blocks sharing one bh's K/V on
// one XCD (2 MB < 4 MB L2) — r10 measured FETCH 69.7 -> 12.4 MB. 128 keys staged per
// barrier pair. exp via RAW v_exp_f32 (__builtin_amdgcn_exp2f): r10's exp2f() was the
// precise OCML routine and cost ~8 us of extra VALU. Pt is WAVE-PRIVATE: no barrier
// between P-write and P-read.
__global__ __launch_bounds__(256) void attn_flash(
    const short* __restrict__ qb, const short* __restrict__ kb, const short* __restrict__ vtb,
    float* __restrict__ merged, short* __restrict__ mergedh, float* __restrict__ colsum)
{
    __shared__ __align__(16) short Kt[2 * 64 * 64];  // two [key j][dk] sub-tiles, XOR-swizzled
    __shared__ __align__(16) short Vt[2 * 64 * 64];  // two [dk d][key j] sub-tiles, XOR-swizzled
    __shared__ __align__(16) short Pt[4 * 32 * 68];  // per-wave 32x64 P tile, stride 68
    const int bh = blockIdx.x, qt = blockIdx.y;
    const int tid = threadIdx.x, wave = tid >> 6, lane = tid & 63;
    const int quad = lane >> 4, ll = lane & 15;
    const short* qp = qb  + (size_t)bh * 1024 * 64;
    const short* kp = kb  + (size_t)bh * 1024 * 64;
    const short* vp = vtb + (size_t)bh * 64 * 1024;

    v8s qa[2][2];
#pragma unroll
    for (int mi = 0; mi < 2; ++mi) {
        int qrow = qt * 128 + wave * 32 + mi * 16 + ll;
        qa[mi][0] = *(const v8s*)(qp + (size_t)qrow * 64 + quad * 8);
        qa[mi][1] = *(const v8s*)(qp + (size_t)qrow * 64 + 32 + quad * 8);
    }

    const v4f zero4 = {0.f, 0.f, 0.f, 0.f};
    v4f oacc[2][4];
    for (int mi = 0; mi < 2; ++mi) for (int nt = 0; nt < 4; ++nt) oacc[mi][nt] = zero4;
    float lsum[2][4];
    for (int mi = 0; mi < 2; ++mi) for (int r = 0; r < 4; ++r) lsum[mi][r] = 0.f;
    short* pw = &Pt[wave * 32 * 68];

    for (int jt2 = 0; jt2 < 8; ++jt2) {
        __syncthreads();
#pragma unroll
        for (int half = 0; half < 2; ++half) {
            int jt = jt2 * 2 + half;
#pragma unroll
            for (int c = 0; c < 2; ++c) {
                int chb = (wave * 2 + c) * 64;
                int ch = chb + lane;
                int row = ch >> 3;
                int gi = ((ch & 7) ^ (row & 7)) * 8;
                gld16(kp + (size_t)(jt * 64 + row) * 64 + gi, &Kt[half * 4096 + chb * 8]);
                gld16(vp + (size_t)row * 1024 + jt * 64 + gi, &Vt[half * 4096 + chb * 8]);
            }
        }
        __syncthreads();

#pragma unroll
        for (int half = 0; half < 2; ++half) {
            const short* Kh = &Kt[half * 4096];
            const short* Vh = &Vt[half * 4096];
            v4f sacc[2][4];
#pragma unroll
            for (int nt = 0; nt < 4; ++nt) {
                int n = nt * 16 + ll;
                int g0 = (quad ^ (n & 7)) * 8;
                int g1 = ((4 + quad) ^ (n & 7)) * 8;
                v8s b0 = *(const v8s*)&Kh[n * 64 + g0];
                v8s b1 = *(const v8s*)&Kh[n * 64 + g1];
#pragma unroll
                for (int mi = 0; mi < 2; ++mi) {
                    v4f s = zero4;
                    s = __builtin_amdgcn_mfma_f32_16x16x32_bf16(qa[mi][0], b0, s, 0, 0, 0);
                    s = __builtin_amdgcn_mfma_f32_16x16x32_bf16(qa[mi][1], b1, s, 0, 0, 0);
                    sacc[mi][nt] = s;
                }
            }
#pragma unroll
            for (int mi = 0; mi < 2; ++mi)
#pragma unroll
                for (int nt = 0; nt < 4; ++nt)
#pragma unroll
                    for (int r = 0; r < 4; ++r) {
                        float e = __builtin_amdgcn_exp2f(sacc[mi][nt][r]);  // raw v_exp_f32; q pre-scaled by log2e
                        lsum[mi][r] += e;
                        pw[(mi * 16 + quad * 4 + r) * 68 + nt * 16 + ll] = f2bf(e);
                    }
            // no __syncthreads: Pt is wave-private, DS ops are in-order within a wave
            v8s pa[2][2];
#pragma unroll
            for (int mi = 0; mi < 2; ++mi) {
                v4s p00 = *(const v4s*)&pw[(mi * 16 + ll) * 68 + quad * 8];
                v4s p01 = *(const v4s*)&pw[(mi * 16 + ll) * 68 + quad * 8 + 4];
                v4s p10 = *(const v4s*)&pw[(mi * 16 + ll) * 68 + 32 + quad * 8];
                v4s p11 = *(const v4s*)&pw[(mi * 16 + ll) * 68 + 32 + quad * 8 + 4];
                pa[mi][0] = __builtin_shufflevector(p00, p01, 0, 1, 2, 3, 4, 5, 6, 7);
                pa[mi][1] = __builtin_shufflevector(p10, p11, 0, 1, 2, 3, 4, 5, 6, 7);
            }
#pragma unroll
            for (int nt = 0; nt < 4; ++nt) {
                int n = nt * 16 + ll;
                int g0 = (quad ^ (n & 7)) * 8;
                int g1 = ((4 + quad) ^ (n & 7)) * 8;
                v8s v0 = *(const v8s*)&Vh[n * 64 + g0];
                v8s v1 = *(const v8s*)&Vh[n * 64 + g1];
#pragma unroll
                for (int mi = 0; mi < 2; ++mi) {
                    oacc[mi][nt] = __builtin_amdgcn_mfma_f32_16x16x32_bf16(pa[mi][0], v0, oacc[mi][nt], 0, 0, 0);
                    oacc[mi][nt] = __builtin_amdgcn_mfma_f32_16x16x32_bf16(pa[mi][1], v1, oacc[mi][nt], 0, 0, 0);
                }
            }
        }
    }

    const int b = bh >> 4, h = bh & 15;
    float csum[4] = {0.f, 0.f, 0.f, 0.f};
#pragma unroll
    for (int mi = 0; mi < 2; ++mi) {
        float linv[4];
#pragma unroll
        for (int r = 0; r < 4; ++r) {
            float s = lsum[mi][r];
            s += __shfl_xor(s, 1); s += __shfl_xor(s, 2);
            s += __shfl_xor(s, 4); s += __shfl_xor(s, 8);
            linv[r] = 1.0f / s;
        }
#pragma unroll
        for (int r = 0; r < 4; ++r) {
            int li = qt * 128 + wave * 32 + mi * 16 + quad * 4 + r;
            size_t rowoff = ((size_t)(b * 1024 + li)) * 1024 + h * 64;
#pragma unroll
            for (int nt = 0; nt < 4; ++nt) {
                int d = nt * 16 + ll;
                float v = oacc[mi][nt][r] * linv[r];
                merged[rowoff + d] = v;
                mergedh[rowoff + d] = f2bf(v);
                csum[nt] += v;
            }
        }
    }
    // per-column partials: combine quads -> 32-row sums, one atomic per column/wave
#pragma unroll
    for (int nt = 0; nt < 4; ++nt) {
        csum[nt] += __shfl_xor(csum[nt], 16);
        csum[nt] += __shfl_xor(csum[nt], 32);
    }
    if (quad == 0) {
#pragma unroll
        for (int nt = 0; nt < 4; ++nt)
            atomicAdd(&colsum[h * 64 + nt * 16 + ll], csum[nt]);
    }
}

// ---------------------------------------------------------------- post-attn: out-proj GEMM + center/split/transpose
// blocks 0..255: out = mergedh @ Wo^T + bo (fp32). blocks 256..1279: center+transpose.
__global__ __launch_bounds__(256) void post_attn(
    const short* __restrict__ A, const short* __restrict__ W, const float* __restrict__ bias,
    float* __restrict__ out,
    const float* __restrict__ merged, const float* __restrict__ colsum,
    short* __restrict__ uth, short* __restrict__ utl)
{
    __shared__ __align__(16) char smem[18432];
    const int bid = blockIdx.x;
    const int tid = threadIdx.x;
    if (bid < 256) {
        short* At = (short*)smem;            // 8 KB
        short* Bt = (short*)(smem + 8192);   // 8 KB
        const int K = 1024;
        const int n0 = (bid & 7) * 128, m0 = (bid >> 3) * 128;
        const int wave = tid >> 6, lane = tid & 63;
        const int quad = lane >> 4, ll = lane & 15;
        const int wr = wave >> 1, wc = wave & 1;
        const v4f zero4 = {0.f, 0.f, 0.f, 0.f};
        v4f acc[4][4];
        for (int i = 0; i < 4; ++i) for (int j = 0; j < 4; ++j) acc[i][j] = zero4;

        for (int k0 = 0; k0 < K; k0 += 32) {
            __syncthreads();
#pragma unroll
            for (int c = 0; c < 2; ++c) {
                int chb = (wave * 2 + c) * 64;
                int ch = chb + lane;
                int row = ch >> 2, col8 = (ch & 3) * 8;
                gld16(A + (size_t)(m0 + row) * K + k0 + col8, &At[chb * 8]);
                gld16(W + (size_t)(n0 + row) * K + k0 + col8, &Bt[chb * 8]);
            }
            __syncthreads();
            v8s af[4], bfr[4];
#pragma unroll
            for (int i = 0; i < 4; ++i) af[i]  = *(const v8s*)&At[(wr * 64 + i * 16 + ll) * 32 + quad * 8];
#pragma unroll
            for (int j = 0; j < 4; ++j) bfr[j] = *(const v8s*)&Bt[(wc * 64 + j * 16 + ll) * 32 + quad * 8];
#pragma unroll
            for (int i = 0; i < 4; ++i)
#pragma unroll
                for (int j = 0; j < 4; ++j)
                    acc[i][j] = __builtin_amdgcn_mfma_f32_16x16x32_bf16(af[i], bfr[j], acc[i][j], 0, 0, 0);
        }

#pragma unroll
        for (int j = 0; j < 4; ++j) {
            int n = n0 + wc * 64 + j * 16 + ll;
            float bb = bias[n];
#pragma unroll
            for (int i = 0; i < 4; ++i) {
                int mbase = m0 + wr * 64 + i * 16 + quad * 4;
#pragma unroll
                for (int r = 0; r < 4; ++r) {
                    int m = mbase + r;
                    out[(size_t)m * 1024 + n] = acc[i][j][r] + bb;
                }
            }
        }
    } else {
        short (*Hh)[72] = (short(*)[72])smem;            // 9216 B
        short (*Hl)[72] = (short(*)[72])(smem + 9216);   // 9216 B
        const int cid = bid - 256;
        const int d0 = (cid & 15) * 64, m0 = (cid >> 4) * 64;
        const int r0 = tid >> 4, c4 = (tid & 15) * 4;
        float mu[4];
#pragma unroll
        for (int e = 0; e < 4; ++e) mu[e] = colsum[d0 + c4 + e] * (1.0f / 4096.0f);
        for (int rr = 0; rr < 64; rr += 16) {
            int m = m0 + rr + r0;
            v4f v = *(const v4f*)(merged + (size_t)m * 1024 + d0 + c4);
#pragma unroll
            for (int e = 0; e < 4; ++e) {
                float u = v[e] - mu[e];
                short h = f2bf(u);
                Hh[c4 + e][rr + r0] = h;
                Hl[c4 + e][rr + r0] = f2bf(u - bf2f(h));
            }
        }
        __syncthreads();
        const int d = tid >> 2, mg = (tid & 3) * 16;
        v8s a0, a1, b0, b1;
#pragma unroll
        for (int e = 0; e < 8; ++e) {
            a0[e] = Hh[d][mg + e]; a1[e] = Hh[d][mg + 8 + e];
            b0[e] = Hl[d][mg + e]; b1[e] = Hl[d][mg + 8 + e];
        }
        size_t off = (size_t)(d0 + d) * 4096 + m0 + mg;
        *(v8s*)(uth + off) = a0; *(v8s*)(uth + off + 8) = a1;
        *(v8s*)(utl + off) = b0; *(v8s*)(utl + off + 8) = b1;
    }
}

// ---------------------------------------------------------------- DeCov GEMM, 128x128 tiles, split-K
// C = Ut @ Ut^T, 8x8 grid of 128-tiles -> 36 upper-tri pairs, K=4096 -> 16 chunks of 256.
__global__ __launch_bounds__(256) void gemm_decov(
    const short* __restrict__ uth, const short* __restrict__ utl, float* __restrict__ cpart)
{
    int p = blockIdx.x, I = 0, rem = p;
    while (rem >= 8 - I) { rem -= 8 - I; ++I; }
    const int J = I + rem;
    const int kbase = blockIdx.y * 256;
    __shared__ __align__(16) short Ah[128 * 32], Al[128 * 32], Bh[128 * 32], Bl[128 * 32];
    const int tid = threadIdx.x;
    const int wave = tid >> 6, lane = tid & 63;
    const int quad = lane >> 4, ll = lane & 15;
    const int wr = wave >> 1, wc = wave & 1;
    const v4f zero4 = {0.f, 0.f, 0.f, 0.f};
    v4f acc[4][4];
    for (int i = 0; i < 4; ++i) for (int j = 0; j < 4; ++j) acc[i][j] = zero4;

    // staging: wave 0->Ah(uth,I) 1->Al(utl,I) 2->Bh(uth,J) 3->Bl(utl,J)
    short* sarr = (wave == 0) ? Ah : (wave == 1) ? Al : (wave == 2) ? Bh : Bl;
    const short* gsrc = (wave & 1) ? utl : uth;
    const int rbase = ((wave < 2) ? I : J) * 128;
    const int srow = lane >> 2, scol = (lane & 3) * 8;

    for (int kk = 0; kk < 256; kk += 32) {
        int k0 = kbase + kk;
        __syncthreads();
#pragma unroll
        for (int c = 0; c < 8; ++c) {
            int row = c * 16 + srow;
            gld16(gsrc + (size_t)(rbase + row) * 4096 + k0 + scol, &sarr[c * 512]);
        }
        __syncthreads();
        v8s bh[4], bl[4];
#pragma unroll
        for (int j = 0; j < 4; ++j) {
            int ro = (wc * 64 + j * 16 + ll) * 32 + quad * 8;
            bh[j] = *(const v8s*)&Bh[ro];
            bl[j] = *(const v8s*)&Bl[ro];
        }
#pragma unroll
        for (int i = 0; i < 4; ++i) {
            int ro = (wr * 64 + i * 16 + ll) * 32 + quad * 8;
            v8s ah = *(const v8s*)&Ah[ro];
            v8s al = *(const v8s*)&Al[ro];
#pragma unroll
            for (int j = 0; j < 4; ++j) {
                acc[i][j] = __builtin_amdgcn_mfma_f32_16x16x32_bf16(ah, bh[j], acc[i][j], 0, 0, 0);
                acc[i][j] = __builtin_amdgcn_mfma_f32_16x16x32_bf16(ah, bl[j], acc[i][j], 0, 0, 0);
                acc[i][j] = __builtin_amdgcn_mfma_f32_16x16x32_bf16(al, bh[j], acc[i][j], 0, 0, 0);
            }
        }
    }

    float* dst = cpart + ((size_t)blockIdx.y * 36 + p) * 16384;
#pragma unroll
    for (int i = 0; i < 4; ++i)
#pragma unroll
        for (int j = 0; j < 4; ++j)
#pragma unroll
            for (int r = 0; r < 4; ++r) {
                int gi2 = wr * 64 + i * 16 + quad * 4 + r;
                int gj2 = wc * 64 + j * 16 + ll;
                dst[gi2 * 128 + gj2] = acc[i][j][r];
            }
}

// ---------------------------------------------------------------- DeCov reduce + final (atomic-only, no fences)
__global__ __launch_bounds__(256) void decov_reduce(
    const float* __restrict__ cpart, float* __restrict__ dtot, int* __restrict__ dcnt,
    float* __restrict__ out)
{
    int p = blockIdx.x, I = 0, rem = p;
    while (rem >= 8 - I) { rem -= 8 - I; ++I; }
    const int J = I + rem;
    const int t = threadIdx.x;
    const int ebase = blockIdx.y * 4096;
    __shared__ float wsums[4];
    float s = 0.f;
#pragma unroll
    for (int it = 0; it < 4; ++it) {
        int e4 = ebase + it * 1024 + t * 4;
        v4f c = {0.f, 0.f, 0.f, 0.f};
#pragma unroll
        for (int kc = 0; kc < 16; ++kc)
            c += *(const v4f*)&cpart[((size_t)kc * 36 + p) * 16384 + e4];
        int gi = I * 128 + (e4 >> 7), colb = J * 128 + (e4 & 127);
#pragma unroll
        for (int k = 0; k < 4; ++k) {
            float cv = c[k];
            if (gi != colb + k) s += cv * cv;
        }
    }
    if (I < J) s *= 2.f;
    s += __shfl_xor(s, 1); s += __shfl_xor(s, 2); s += __shfl_xor(s, 4);
    s += __shfl_xor(s, 8); s += __shfl_xor(s, 16); s += __shfl_xor(s, 32);
    if ((t & 63) == 0) wsums[t >> 6] = s;
    __syncthreads();
    if (t == 0) {
        float blk = wsums[0] + wsums[1] + wsums[2] + wsums[3];
        float o = atomicAdd(dtot, blk);
        int old = atomicAdd(dcnt, 1 + (int)(o * 0.0f));
        if (old == 143) {
            float tot = atomicAdd(dtot, 0.0f);   // RMW returns the coherent full sum
            // C = raw/4096; decov = 0.5 * sum_offdiag C^2
            out[4194304] = 0.5f * tot / (4096.0f * 4096.0f);
        }
    }
}

// ---------------------------------------------------------------- launch
extern "C" void kernel_launch(void* const* d_in, const int* in_sizes, int n_in,
                              void* d_out, int out_size, void* d_ws, size_t ws_size,
                              hipStream_t stream) {
    const float* x  = (const float*)d_in[0];
    const float* Wq = (const float*)d_in[1];
    const float* bq = (const float*)d_in[2];
    const float* Wk = (const float*)d_in[3];
    const float* bk = (const float*)d_in[4];
    const float* Wv = (const float*)d_in[5];
    const float* bv = (const float*)d_in[6];
    const float* Wo = (const float*)d_in[7];
    const float* bo = (const float*)d_in[8];
    float* out = (float*)d_out;
    char* ws = (char*)d_ws;
    const size_t MB = 1ull << 20;
    short* xb      = (short*)(ws);              //  8 MB [4096][1024]
    short* wqb     = (short*)(ws + 8  * MB);    //  2 MB
    short* wkb     = (short*)(ws + 10 * MB);
    short* wvb     = (short*)(ws + 12 * MB);
    short* wob     = (short*)(ws + 14 * MB);
    short* qb      = (short*)(ws + 16 * MB);    //  8 MB [bh][l][dk] (q pre-scaled 1/8*log2e)
    short* kb      = (short*)(ws + 24 * MB);    //  8 MB [bh][l][dk]
    short* vtb     = (short*)(ws + 32 * MB);    //  8 MB [bh][dk][l]
    float* merged  = (float*)(ws + 40 * MB);    // 16 MB [4096][1024] fp32
    short* mergedh = (short*)(ws + 56 * MB);    //  8 MB bf16
    short* uth     = (short*)(ws + 65 * MB);    //  8 MB [1024][4096]
    short* utl     = (short*)(ws + 73 * MB);    //  8 MB
    float* dtot    = (float*)(ws + 81 * MB);    //  4 B
    int*   dcnt    = (int*)(ws + 81 * MB + 64); //  4 B
    float* colsum  = (float*)(ws + 81 * MB + 4096); // 4 KB
    float* cpart   = (float*)(ws);              // 37.7 MB [16][36][16384] (reuses dead 0-40MB region)

    hipLaunchKernelGGL(cvt_bf16, dim3(8192), dim3(256), 0, stream,
                       x, Wq, Wk, Wv, Wo, xb, wqb, wkb, wvb, wob, colsum, dtot, dcnt);
    hipLaunchKernelGGL(gemm_qkv, dim3(8, 32, 3), dim3(256), 0, stream,
                       xb, wqb, wkb, wvb, bq, bk, bv, qb, kb, vtb);
    hipLaunchKernelGGL(attn_flash, dim3(64, 8), dim3(256), 0, stream,
                       qb, kb, vtb, merged, mergedh, colsum);
    hipLaunchKernelGGL(post_attn, dim3(1280), dim3(256), 0, stream,
                       mergedh, wob, bo, out, merged, colsum, uth, utl);
    hipLaunchKernelGGL(gemm_decov, dim3(36, 16), dim3(256), 0, stream, uth, utl, cpart);
    hipLaunchKernelGGL(decov_reduce, dim3(36, 4), dim3(256), 0, stream, cpart, dtot, dcnt, out);
}